// Round 1
// baseline (683.116 us; speedup 1.0000x reference)
//
#include <hip/hip_runtime.h>
#include <cstdint>

typedef __bf16 bf16x8 __attribute__((ext_vector_type(8)));
typedef float f32x4 __attribute__((ext_vector_type(4)));
typedef unsigned short u16x8 __attribute__((ext_vector_type(8)));

#define DEV static __device__ __forceinline__

constexpr int NB = 8;      // batch
constexpr int NC = 512;    // channels C
constexpr int NS = 16384;  // spatial N = H*W
constexpr int ND = 64;     // d = C/8
constexpr int SK = 32;     // split-K blocks in kernel B
constexpr float FPARAM = 10.0f;
constexpr float FEPS = 1e-6f;

DEV unsigned short f2bf(float f) {
  uint32_t u = __builtin_bit_cast(uint32_t, f);
  u += 0x7fffu + ((u >> 16) & 1u);
  return (unsigned short)(u >> 16);
}
DEV float bf2f(unsigned short h) {
  uint32_t u = ((uint32_t)h) << 16;
  return __builtin_bit_cast(float, u);
}
DEV float fmap(float t) {  // 10*relu(t) + exp(10*min(t,0))
  float p = fmaxf(t, 0.0f);
  float m = fminf(t, 0.0f);
  return FPARAM * p + __expf(FPARAM * m);
}
DEV f32x4 mfma16(bf16x8 a, bf16x8 b, f32x4 c) {
  return __builtin_amdgcn_mfma_f32_16x16x32_bf16(a, b, c, 0, 0, 0);
}
// direct 16B bf16 fragment load from global (K-contiguous rows)
DEV bf16x8 ld_bf8(const unsigned short* p) {
  uint4 u = *(const uint4*)p;
  return __builtin_bit_cast(bf16x8, u);
}
// 8x f32 -> bf16x8 in-register conversion
DEV bf16x8 cvt8(float4 a, float4 b) {
  u16x8 t;
  t[0] = f2bf(a.x); t[1] = f2bf(a.y); t[2] = f2bf(a.z); t[3] = f2bf(a.w);
  t[4] = f2bf(b.x); t[5] = f2bf(b.y); t[6] = f2bf(b.z); t[7] = f2bf(b.w);
  return __builtin_bit_cast(bf16x8, t);
}

// ---- LDS tile helpers (kernelA only): [rows][64] bf16, XOR-swizzled 16B chunks
DEV void tile_store4(unsigned short* t, int row, int k, ushort4 v) {  // k%4==0
  int ch = (k >> 3) ^ (row & 7);
  *(ushort4*)(t + row * 64 + ch * 8 + (k & 7)) = v;
}
DEV bf16x8 tile_frag(const unsigned short* t, int row, int k) {  // k%8==0
  int ch = (k >> 3) ^ (row & 7);
  uint4 u = *(const uint4*)(t + row * 64 + ch * 8);
  return __builtin_bit_cast(bf16x8, u);
}

// ============================================================================
// Kernel P (prep): Wq,Wk -> Wqkb[128][512] bf16 ; Wv -> Wvb[512][512] bf16 ;
// zero Ksum. Tiny (~1.3 MB read) — runs once per invocation.
// ============================================================================
__global__ __launch_bounds__(256) void kernelP(
    const float* __restrict__ Wq, const float* __restrict__ Wk,
    const float* __restrict__ Wv, unsigned short* __restrict__ Wqkb,
    unsigned short* __restrict__ Wvb, float* __restrict__ Ksum) {
  const int tid = blockIdx.x * 256 + threadIdx.x;
  const int stride = gridDim.x * 256;
  if (tid < NB * ND) Ksum[tid] = 0.f;
  for (int p = tid; p < ND * NC / 4; p += stride) {
    float4 v = ((const float4*)Wq)[p];
    ((ushort4*)Wqkb)[p] = make_ushort4(f2bf(v.x), f2bf(v.y), f2bf(v.z), f2bf(v.w));
  }
  for (int p = tid; p < ND * NC / 4; p += stride) {
    float4 v = ((const float4*)Wk)[p];
    ((ushort4*)(Wqkb + ND * NC))[p] =
        make_ushort4(f2bf(v.x), f2bf(v.y), f2bf(v.z), f2bf(v.w));
  }
  for (int p = tid; p < NC * NC / 4; p += stride) {
    float4 v = ((const float4*)Wv)[p];
    ((ushort4*)Wvb)[p] = make_ushort4(f2bf(v.x), f2bf(v.y), f2bf(v.z), f2bf(v.w));
  }
}

// ============================================================================
// Kernel A: Q/K projection + bias + feature map + Ksum (f32 atomics).
// W fragments direct from global bf16 (L2-resident); x transposed through
// double-buffered LDS with register prefetch -> ONE barrier per K-step.
// ============================================================================
__global__ __launch_bounds__(256) void kernelA(
    const float* __restrict__ x, const unsigned short* __restrict__ Wqk,
    const float* __restrict__ bq, const float* __restrict__ bk,
    unsigned short* __restrict__ Kp, unsigned short* __restrict__ Qt,
    float* __restrict__ Ksum) {
  __shared__ unsigned short sX[2][128 * 64];  // [n][c] transposed x, dbuf
  const int t = threadIdx.x;
  const int lane = t & 63, wave = t >> 6;
  const int wm = wave >> 1, wn = wave & 1;  // 2x2 wave grid, 64x64 each
  const int l15 = lane & 15, q = lane >> 4;
  const int n0 = blockIdx.x * 128;
  const int b = blockIdx.y;
  const float* xb = x + (size_t)b * NC * NS;

  f32x4 acc[4][4];
  const f32x4 zero = {0.f, 0.f, 0.f, 0.f};
  for (int i = 0; i < 4; i++)
    for (int j = 0; j < 4; j++) acc[i][j] = zero;

  const int qq = t & 3, grp = t >> 2;
  const int n4 = (grp & 31) * 4, cb = (grp >> 5) * 4;
  const int shfl_base = lane & ~3;

  float4 pf[8];
#pragma unroll
  for (int it = 0; it < 8; it++)
    pf[it] = *(const float4*)(xb + (size_t)(cb + qq + it * 8) * NS + n0 + n4);

  for (int cc = 0; cc < 8; cc++) {
    unsigned short* sx = sX[cc & 1];
    const int c0 = cc * 64;
    // store phase: 4x4 shfl lane-transpose + cvt from prefetched regs
#pragma unroll
    for (int it = 0; it < 8; it++) {
      float4 v = pf[it];
      float vv[4] = {v.x, v.y, v.z, v.w};
      float o[4];
#pragma unroll
      for (int r = 0; r < 4; r++) {
        int j = (qq + r) & 3;
        float send = vv[(qq - r) & 3];
        o[j] = __shfl(send, shfl_base + j);
      }
      tile_store4(sx, n4 + qq, it * 8 + cb,
                  make_ushort4(f2bf(o[0]), f2bf(o[1]), f2bf(o[2]), f2bf(o[3])));
    }
    // issue next chunk's loads before the barrier (overlap with MFMA)
    if (cc < 7) {
      const int c1 = c0 + 64;
#pragma unroll
      for (int it = 0; it < 8; it++)
        pf[it] = *(const float4*)(xb + (size_t)(c1 + cb + qq + it * 8) * NS + n0 + n4);
    }
    __syncthreads();  // single barrier: next store goes to the other buffer
#pragma unroll
    for (int kk = 0; kk < 64; kk += 32) {
      int kb = kk + q * 8;
      bf16x8 af[4], bg[4];
#pragma unroll
      for (int i = 0; i < 4; i++)
        af[i] = ld_bf8(Wqk + (size_t)(wm * 64 + i * 16 + l15) * NC + c0 + kb);
#pragma unroll
      for (int j = 0; j < 4; j++) bg[j] = tile_frag(sx, wn * 64 + j * 16 + l15, kb);
#pragma unroll
      for (int i = 0; i < 4; i++)
#pragma unroll
        for (int j = 0; j < 4; j++) acc[i][j] = mfma16(af[i], bg[j], acc[i][j]);
    }
  }

  // epilogue: D layout col=lane&15 (n), row=(lane>>4)*4+r (m)
  if (wm == 0) {  // Q rows -> Qt[b][n][m]
#pragma unroll
    for (int i = 0; i < 4; i++) {
      int mb = i * 16 + q * 4;
      float b0 = bq[mb + 0], b1 = bq[mb + 1], b2 = bq[mb + 2], b3 = bq[mb + 3];
#pragma unroll
      for (int j = 0; j < 4; j++) {
        int n = n0 + wn * 64 + j * 16 + l15;
        f32x4 v = acc[i][j];
        ushort4 o = make_ushort4(f2bf(fmap(v[0] + b0)), f2bf(fmap(v[1] + b1)),
                                 f2bf(fmap(v[2] + b2)), f2bf(fmap(v[3] + b3)));
        *(ushort4*)(Qt + ((size_t)b * NS + n) * ND + mb) = o;
      }
    }
  } else {  // K rows -> Kp[b][m][n] + Ksum f32 atomics
#pragma unroll
    for (int i = 0; i < 4; i++) {
      int mb = i * 16 + q * 4;
      float b0 = bk[mb + 0], b1 = bk[mb + 1], b2 = bk[mb + 2], b3 = bk[mb + 3];
      float ks0 = 0.f, ks1 = 0.f, ks2 = 0.f, ks3 = 0.f;
#pragma unroll
      for (int j = 0; j < 4; j++) {
        int n = n0 + wn * 64 + j * 16 + l15;
        f32x4 v = acc[i][j];
        float f0 = fmap(v[0] + b0), f1 = fmap(v[1] + b1);
        float f2 = fmap(v[2] + b2), f3 = fmap(v[3] + b3);
        Kp[((size_t)b * ND + mb + 0) * NS + n] = f2bf(f0);
        Kp[((size_t)b * ND + mb + 1) * NS + n] = f2bf(f1);
        Kp[((size_t)b * ND + mb + 2) * NS + n] = f2bf(f2);
        Kp[((size_t)b * ND + mb + 3) * NS + n] = f2bf(f3);
        ks0 += f0; ks1 += f1; ks2 += f2; ks3 += f3;
      }
#pragma unroll
      for (int ms = 1; ms < 16; ms <<= 1) {  // reduce over n (16 l15 lanes)
        ks0 += __shfl_xor(ks0, ms);
        ks1 += __shfl_xor(ks1, ms);
        ks2 += __shfl_xor(ks2, ms);
        ks3 += __shfl_xor(ks3, ms);
      }
      if (l15 == 0) {
        atomicAdd(&Ksum[b * ND + mb + 0], ks0);
        atomicAdd(&Ksum[b * ND + mb + 1], ks1);
        atomicAdd(&Ksum[b * ND + mb + 2], ks2);
        atomicAdd(&Ksum[b * ND + mb + 3], ks3);
      }
    }
  }
}

// ============================================================================
// Kernel B: split-K partials KXt[m][c'] = sum_n K'[m][n] * x[c'][n].
// Barrier-free, NO LDS: Kp fragments direct from global (L1/L2-hot within
// block), x fragments loaded f32 + converted in-register (no reuse exists).
// Grid: 128 flat (s x quarter, mod-8 swizzled so Kp-sharing blocks co-XCD) x B.
// ============================================================================
__global__ __launch_bounds__(256) void kernelB(
    const float* __restrict__ x, const unsigned short* __restrict__ Kp,
    float* __restrict__ Pp) {
  const int t = threadIdx.x;
  const int lane = t & 63, wave = t >> 6;
  const int l15 = lane & 15, q = lane >> 4;
  const int id = blockIdx.x, b = blockIdx.y;
  const int s = ((id >> 5) << 3) + (id & 7);  // 0..31
  const int quarter = (id >> 3) & 3;          // 0..3 (128 c' each)
  const int nbase = s * (NS / SK);
  const unsigned short* kpb = Kp + (size_t)b * ND * NS;
  const float* xq = x + ((size_t)b * NC + quarter * 128 + wave * 32) * NS;

  f32x4 acc[4][2];
  const f32x4 zero = {0.f, 0.f, 0.f, 0.f};
  for (int i = 0; i < 4; i++)
    for (int j = 0; j < 2; j++) acc[i][j] = zero;

#pragma unroll 2
  for (int nc = 0; nc < NS / SK; nc += 32) {
    int nb = nbase + nc + q * 8;
    bf16x8 af[4], bg[2];
#pragma unroll
    for (int i = 0; i < 4; i++)
      af[i] = ld_bf8(kpb + (size_t)(i * 16 + l15) * NS + nb);
#pragma unroll
    for (int j = 0; j < 2; j++) {
      const float* px = xq + (size_t)(j * 16 + l15) * NS + nb;
      bg[j] = cvt8(*(const float4*)px, *(const float4*)(px + 4));
    }
#pragma unroll
    for (int i = 0; i < 4; i++)
#pragma unroll
      for (int j = 0; j < 2; j++) acc[i][j] = mfma16(af[i], bg[j], acc[i][j]);
  }

  float* pp = Pp + ((size_t)b * SK + s) * ND * NC;
#pragma unroll
  for (int i = 0; i < 4; i++) {
    int mb = i * 16 + q * 4;
#pragma unroll
    for (int j = 0; j < 2; j++) {
      int cp = quarter * 128 + wave * 32 + j * 16 + l15;
      f32x4 v = acc[i][j];
#pragma unroll
      for (int r = 0; r < 4; r++) pp[(size_t)(mb + r) * NC + cp] = v[r];
    }
  }
}

// ============================================================================
// Kernel C1: reduce split-K partials -> KXt[b][m][c']
// ============================================================================
__global__ __launch_bounds__(256) void kernelC1(
    const float* __restrict__ Pp, float* __restrict__ KXt) {
  const int m = blockIdx.x, b = blockIdx.y, t = threadIdx.x;
  float a0 = 0.f, a1 = 0.f;
#pragma unroll 8
  for (int s = 0; s < SK; s++) {
    const float* p = Pp + (((size_t)b * SK + s) * ND + m) * NC;
    a0 += p[t];
    a1 += p[t + 256];
  }
  float* o = KXt + ((size_t)b * ND + m) * NC;
  o[t] = a0;
  o[t + 256] = a1;
}

// ============================================================================
// Kernel C2: KVT[b][c][m] = sum_c' KXt[m][c'] Wv[c][c'] + Ksum[m]*bv[c]
// Barrier-free, no LDS, 4 waves (2x2 of 32x32), direct fragments.
// ============================================================================
__global__ __launch_bounds__(256) void kernelC2(
    const float* __restrict__ KXt, const unsigned short* __restrict__ Wvb,
    const float* __restrict__ bv, const float* __restrict__ Ksum,
    unsigned short* __restrict__ KVT) {
  const int t = threadIdx.x;
  const int lane = t & 63, wave = t >> 6;
  const int wm = wave >> 1, wn = wave & 1;
  const int l15 = lane & 15, q = lane >> 4;
  const int ct = blockIdx.x, b = blockIdx.y;

  f32x4 acc[2][2];
  const f32x4 zero = {0.f, 0.f, 0.f, 0.f};
  for (int i = 0; i < 2; i++)
    for (int j = 0; j < 2; j++) acc[i][j] = zero;

#pragma unroll 2
  for (int c0 = 0; c0 < NC; c0 += 32) {
    int kb = c0 + q * 8;
    bf16x8 af[2], bg[2];
#pragma unroll
    for (int i = 0; i < 2; i++)
      af[i] = ld_bf8(Wvb + (size_t)(ct * 64 + wm * 32 + i * 16 + l15) * NC + kb);
#pragma unroll
    for (int j = 0; j < 2; j++) {
      const float* px = KXt + ((size_t)b * ND + wn * 32 + j * 16 + l15) * NC + kb;
      bg[j] = cvt8(*(const float4*)px, *(const float4*)(px + 4));
    }
#pragma unroll
    for (int i = 0; i < 2; i++)
#pragma unroll
      for (int j = 0; j < 2; j++) acc[i][j] = mfma16(af[i], bg[j], acc[i][j]);
  }

#pragma unroll
  for (int j = 0; j < 2; j++) {
    int m = wn * 32 + j * 16 + l15;
    float km = Ksum[b * ND + m];
#pragma unroll
    for (int i = 0; i < 2; i++) {
      f32x4 v = acc[i][j];
#pragma unroll
      for (int r = 0; r < 4; r++) {
        int c = ct * 64 + wm * 32 + i * 16 + q * 4 + r;
        KVT[((size_t)b * NC + c) * ND + m] = f2bf(v[r] + km * bv[c]);
      }
    }
  }
}

// ============================================================================
// Kernel D: out = x + gamma * norm[n] * (KVT @ Qt^T). Fragments direct from
// global (KVT L2-resident, Qt K-contiguous). acc lifetime split into two
// c-halves (64 fewer VGPRs) for occupancy. Only 2 barriers (norm), then
// barrier-free MFMA + streaming epilogue.
// Grid: 256 flat (chalf x ntile, mod-8 swizzled) x B.
// ============================================================================
__global__ __launch_bounds__(256) void kernelD(
    const float* __restrict__ x, const unsigned short* __restrict__ Qt,
    const unsigned short* __restrict__ KVT, const float* __restrict__ Ksum,
    const float* __restrict__ gamma, float* __restrict__ out) {
  __shared__ float sN[128];
  __shared__ float sKs[64];
  const int t = threadIdx.x;
  const int lane = t & 63, wave = t >> 6;
  const int wm = wave >> 1, wn = wave & 1;  // wave tile 128c x 64n
  const int l15 = lane & 15, q = lane >> 4;
  const int id = blockIdx.x, b = blockIdx.y;
  const int nblk = ((id >> 4) << 3) + (id & 7);  // 0..127
  const int chalf = (id >> 3) & 1;
  const int n0 = nblk * 128, c0 = chalf * 256;

  if (t < 64) sKs[t] = Ksum[b * ND + t] + FEPS;
  __syncthreads();
  if (t < 128) {
    const unsigned short* qrow = Qt + ((size_t)b * NS + n0 + t) * ND;
    float sum = 0.f;
#pragma unroll
    for (int mm = 0; mm < 64; mm += 8) {
      uint4 u = *(const uint4*)(qrow + mm);
      const unsigned short* us = (const unsigned short*)&u;
#pragma unroll
      for (int e = 0; e < 8; e++) sum += bf2f(us[e]) * sKs[mm + e];
    }
    sN[t] = 1.0f / sum;
  }
  __syncthreads();

  const float g = gamma[0];
#pragma unroll 1
  for (int h = 0; h < 2; h++) {
    f32x4 acc[4][4];
    const f32x4 zero = {0.f, 0.f, 0.f, 0.f};
    for (int i = 0; i < 4; i++)
      for (int j = 0; j < 4; j++) acc[i][j] = zero;
#pragma unroll
    for (int kk = 0; kk < 64; kk += 32) {
      int kb = kk + q * 8;
      bf16x8 af[4], bg[4];
#pragma unroll
      for (int i = 0; i < 4; i++)
        af[i] = ld_bf8(KVT +
                       ((size_t)b * NC + c0 + wm * 128 + h * 64 + i * 16 + l15) * ND + kb);
#pragma unroll
      for (int j = 0; j < 4; j++)
        bg[j] = ld_bf8(Qt + ((size_t)b * NS + n0 + wn * 64 + j * 16 + l15) * ND + kb);
#pragma unroll
      for (int i = 0; i < 4; i++)
#pragma unroll
        for (int j = 0; j < 4; j++) acc[i][j] = mfma16(af[i], bg[j], acc[i][j]);
    }
#pragma unroll
    for (int i = 0; i < 4; i++) {
      int cb = c0 + wm * 128 + h * 64 + i * 16 + q * 4;
#pragma unroll
      for (int j = 0; j < 4; j++) {
        int nl = wn * 64 + j * 16 + l15;
        float nr = sN[nl] * g;
        size_t base = ((size_t)b * NC + cb) * NS + n0 + nl;
        f32x4 v = acc[i][j];
#pragma unroll
        for (int r = 0; r < 4; r++) {
          size_t idx = base + (size_t)r * NS;
          out[idx] = x[idx] + nr * v[r];
        }
      }
    }
  }
}

extern "C" void kernel_launch(void* const* d_in, const int* in_sizes, int n_in,
                              void* d_out, int out_size, void* d_ws, size_t ws_size,
                              hipStream_t stream) {
  (void)in_sizes; (void)n_in; (void)out_size; (void)ws_size;
  const float* x = (const float*)d_in[0];
  const float* Wq = (const float*)d_in[1];
  const float* bq = (const float*)d_in[2];
  const float* Wk = (const float*)d_in[3];
  const float* bk = (const float*)d_in[4];
  const float* Wv = (const float*)d_in[5];
  const float* bv = (const float*)d_in[6];
  const float* gamma = (const float*)d_in[7];
  float* out = (float*)d_out;

  char* ws = (char*)d_ws;
  unsigned short* Qt = (unsigned short*)ws;  ws += (size_t)NB * NS * ND * 2;      // 16.78 MB
  unsigned short* Kp = (unsigned short*)ws;  ws += (size_t)NB * ND * NS * 2;      // 16.78 MB
  float* Pp = (float*)ws;                    ws += (size_t)NB * SK * ND * NC * 4; // 33.55 MB
  float* KXt = (float*)ws;                   ws += (size_t)NB * ND * NC * 4;      // 1 MB
  float* Ksum = (float*)ws;                  ws += (size_t)NB * ND * 4;           // 2 KB
  unsigned short* KVT = (unsigned short*)ws; ws += (size_t)NB * NC * ND * 2;      // 0.5 MB
  unsigned short* Wqkb = (unsigned short*)ws; ws += (size_t)2 * ND * NC * 2;      // 128 KB
  unsigned short* Wvb = (unsigned short*)ws;  ws += (size_t)NC * NC * 2;          // 512 KB

  kernelP<<<dim3(64), dim3(256), 0, stream>>>(Wq, Wk, Wv, Wqkb, Wvb, Ksum);
  kernelA<<<dim3(NS / 128, NB), dim3(256), 0, stream>>>(x, Wqkb, bq, bk, Kp, Qt, Ksum);
  kernelB<<<dim3(128, NB), dim3(256), 0, stream>>>(x, Kp, Pp);
  kernelC1<<<dim3(ND, NB), dim3(256), 0, stream>>>(Pp, KXt);
  kernelC2<<<dim3(NC / 64, NB), dim3(256), 0, stream>>>(KXt, Wvb, bv, Ksum, KVT);
  kernelD<<<dim3(256, NB), dim3(256), 0, stream>>>(x, Qt, KVT, Ksum, gamma, out);
}

// Round 2
// 674.576 us; speedup vs baseline: 1.0127x; 1.0127x over previous
//
#include <hip/hip_runtime.h>
#include <cstdint>

typedef __bf16 bf16x8 __attribute__((ext_vector_type(8)));
typedef float f32x4 __attribute__((ext_vector_type(4)));

#define DEV static __device__ __forceinline__

constexpr int NB = 8;      // batch
constexpr int NC = 512;    // channels C
constexpr int NS = 16384;  // spatial N = H*W
constexpr int ND = 64;     // d = C/8
constexpr int SK = 32;     // split-K slabs (512 n each)
constexpr float FPARAM = 10.0f;
constexpr float FEPS = 1e-6f;

DEV unsigned short f2bf(float f) {
  uint32_t u = __builtin_bit_cast(uint32_t, f);
  u += 0x7fffu + ((u >> 16) & 1u);
  return (unsigned short)(u >> 16);
}
DEV float bf2f(unsigned short h) {
  uint32_t u = ((uint32_t)h) << 16;
  return __builtin_bit_cast(float, u);
}
DEV float fmap(float t) {  // 10*relu(t) + exp(10*min(t,0))
  float p = fmaxf(t, 0.0f);
  float m = fminf(t, 0.0f);
  return FPARAM * p + __expf(FPARAM * m);
}
DEV f32x4 mfma16(bf16x8 a, bf16x8 b, f32x4 c) {
  return __builtin_amdgcn_mfma_f32_16x16x32_bf16(a, b, c, 0, 0, 0);
}
DEV bf16x8 ld_bf8(const unsigned short* p) {
  uint4 u = *(const uint4*)p;
  return __builtin_bit_cast(bf16x8, u);
}

// ---- LDS tile helpers: [rows][64] bf16, XOR-swizzled 8-elem (16B) chunks
DEV void tile_store4(unsigned short* t, int row, int k, ushort4 v) {  // k%4==0
  int ch = (k >> 3) ^ (row & 7);
  *(ushort4*)(t + row * 64 + ch * 8 + (k & 7)) = v;
}
DEV void tile_store8(unsigned short* t, int row, int k, uint4 v) {  // k%8==0
  int ch = (k >> 3) ^ (row & 7);
  *(uint4*)(t + row * 64 + ch * 8) = v;
}
DEV void tile_store1(unsigned short* t, int row, int k, unsigned short v) {
  int ch = (k >> 3) ^ (row & 7);
  t[row * 64 + ch * 8 + (k & 7)] = v;
}
DEV bf16x8 tile_frag(const unsigned short* t, int row, int k) {  // k%8==0
  int ch = (k >> 3) ^ (row & 7);
  uint4 u = *(const uint4*)(t + row * 64 + ch * 8);
  return __builtin_bit_cast(bf16x8, u);
}
DEV uint4 tile_frag_u(const unsigned short* t, int row, int k) {  // k%8==0
  int ch = (k >> 3) ^ (row & 7);
  return *(const uint4*)(t + row * 64 + ch * 8);
}

// ============================================================================
// Kernel P (prep): Wq,Wk -> Wqkb[128][512] bf16. Tiny.
// ============================================================================
__global__ __launch_bounds__(256) void kernelP(
    const float* __restrict__ Wq, const float* __restrict__ Wk,
    unsigned short* __restrict__ Wqkb) {
  const int tid = blockIdx.x * 256 + threadIdx.x;
  const int stride = gridDim.x * 256;
  for (int p = tid; p < ND * NC / 4; p += stride) {
    float4 v = ((const float4*)Wq)[p];
    ((ushort4*)Wqkb)[p] = make_ushort4(f2bf(v.x), f2bf(v.y), f2bf(v.z), f2bf(v.w));
  }
  for (int p = tid; p < ND * NC / 4; p += stride) {
    float4 v = ((const float4*)Wk)[p];
    ((ushort4*)(Wqkb + ND * NC))[p] =
        make_ushort4(f2bf(v.x), f2bf(v.y), f2bf(v.z), f2bf(v.w));
  }
}

// ============================================================================
// Kernel A (FUSED A+B): per 512-n slab:
//  - stage x chunk (64c x 64n) ONCE into two LDS layouts:
//      sXT [n][c] (shfl 4x4 transpose) for phase-1, sXN [c][n] for phase-2
//  - phase 1: Q/K = Wqk @ x over c (W fragments direct from global bf16)
//  - K' -> fmap -> 8KB LDS tile (fixes operand layout for phase 2) + Ksum
//  - Q  -> fmap -> LDS bounce -> Qt written as 1KB-contiguous rows
//  - phase 2: KXt_partial[64 m][512 c'] += K'[m][n] x[c'][n], acc in regs
// Writes: Qt (16.8MB), Pp split-K partials (33.5MB), KsP. x read ONCE.
// Grid (32 slabs, 8 b) = 256 blocks, 512 threads, LDS 80KB -> 1 block/CU.
// ============================================================================
__global__ __launch_bounds__(512) void kernelA(
    const float* __restrict__ x, const unsigned short* __restrict__ Wqk,
    const float* __restrict__ bq, const float* __restrict__ bk,
    unsigned short* __restrict__ Qt, float* __restrict__ Pp,
    float* __restrict__ KsP) {
  __shared__ unsigned short sXN[512 * 64];     // 64KB natural [c][n]
  __shared__ unsigned short sXT[2][64 * 64];   // 16KB dbuf transposed [n][c]
  __shared__ float sKs[64];
  // overlays (live only after phase-1 of a chunk, dead before next stage):
  unsigned short* sKp = sXT[0];  // K' tile [64 m][64 n]
  unsigned short* sQt = sXT[1];  // Q  tile [64 n][64 m]

  const int t = threadIdx.x;
  const int lane = t & 63, wave = t >> 6;     // 8 waves
  const int l15 = lane & 15, q = lane >> 4;
  const int wm = wave >> 1, wn = wave & 1;    // phase-1 grid: 4m x 2n
  const int w2m = wave >> 2, w2c = wave & 3;  // phase-2 grid: 2m x 4c'
  const int s = blockIdx.x, b = blockIdx.y;
  const int nbase = s * 512;
  const float* xb = x + (size_t)b * NC * NS;

  // per-thread bias for the 8 (i,r) rows this thread owns in phase 1
  float bias[2][4];
  {
    const float* bb = (wm < 2) ? bq : bk;
    int mb = (wm & 1) * 32;
    for (int i = 0; i < 2; i++)
      for (int r = 0; r < 4; r++) bias[i][r] = bb[mb + i * 16 + q * 4 + r];
  }
  if (t < 64) sKs[t] = 0.f;

  const int qq = t & 3, grp = t >> 2;   // staging decomposition
  const int n4 = (grp & 15) * 4;        // 0..60
  const int cb4 = (grp >> 4) * 4;       // 0..28
  const int shfl_base = lane & ~3;

  f32x4 acc2[2][8];  // KXt partial: wave tile 32m x 128c'
  const f32x4 zero = {0.f, 0.f, 0.f, 0.f};
  for (int i = 0; i < 2; i++)
    for (int j = 0; j < 8; j++) acc2[i][j] = zero;

  for (int nch = 0; nch < 8; nch++) {
    const int n0l = nch * 64;
    f32x4 acc1[2][2];  // Q/K: wave tile 32m x 32n
    for (int i = 0; i < 2; i++)
      for (int j = 0; j < 2; j++) acc1[i][j] = zero;

    for (int cs = 0; cs < 8; cs++) {
      const int c0 = cs * 64;
      unsigned short* xt = sXT[cs & 1];
#pragma unroll
      for (int it = 0; it < 2; it++) {
        int c_l = cb4 + qq + it * 32;
        float4 v = *(const float4*)(xb + (size_t)(c0 + c_l) * NS + nbase + n0l + n4);
        tile_store4(sXN, c0 + c_l, n4,
                    make_ushort4(f2bf(v.x), f2bf(v.y), f2bf(v.z), f2bf(v.w)));
        float vv[4] = {v.x, v.y, v.z, v.w};
        float o[4];
#pragma unroll
        for (int r = 0; r < 4; r++) {
          int j = (qq + r) & 3;
          float send = vv[(qq - r) & 3];
          o[j] = __shfl(send, shfl_base + j);
        }
        tile_store4(xt, n4 + qq, cb4 + it * 32,
                    make_ushort4(f2bf(o[0]), f2bf(o[1]), f2bf(o[2]), f2bf(o[3])));
      }
      __syncthreads();
#pragma unroll
      for (int kk = 0; kk < 64; kk += 32) {
        int kb = kk + q * 8;
        bf16x8 af[2], bg[2];
#pragma unroll
        for (int i = 0; i < 2; i++)
          af[i] = ld_bf8(Wqk + (size_t)(wm * 32 + i * 16 + l15) * NC + c0 + kb);
#pragma unroll
        for (int j = 0; j < 2; j++)
          bg[j] = tile_frag(xt, wn * 32 + j * 16 + l15, kb);
#pragma unroll
        for (int i = 0; i < 2; i++)
#pragma unroll
          for (int j = 0; j < 2; j++) acc1[i][j] = mfma16(af[i], bg[j], acc1[i][j]);
      }
    }
    __syncthreads();  // phase-1 done; sXT overlays now writable

    if (wm >= 2) {  // K rows: fmap -> sKp tile + Ksum partial
      int mrow = (wm - 2) * 32;
#pragma unroll
      for (int i = 0; i < 2; i++) {
        float ks[4] = {0.f, 0.f, 0.f, 0.f};
#pragma unroll
        for (int j = 0; j < 2; j++) {
          int nl = wn * 32 + j * 16 + l15;
#pragma unroll
          for (int r = 0; r < 4; r++) {
            float f = fmap(acc1[i][j][r] + bias[i][r]);
            tile_store1(sKp, mrow + i * 16 + q * 4 + r, nl, f2bf(f));
            ks[r] += f;
          }
        }
#pragma unroll
        for (int ms = 1; ms < 16; ms <<= 1)
#pragma unroll
          for (int r = 0; r < 4; r++) ks[r] += __shfl_xor(ks[r], ms);
        if (l15 == 0)
#pragma unroll
          for (int r = 0; r < 4; r++)
            atomicAdd(&sKs[mrow + i * 16 + q * 4 + r], ks[r]);
      }
    } else {  // Q rows: fmap -> sQt [n][m] (4 consecutive m per lane = ushort4)
      int mrow = wm * 32;
#pragma unroll
      for (int i = 0; i < 2; i++)
#pragma unroll
        for (int j = 0; j < 2; j++) {
          int nl = wn * 32 + j * 16 + l15;
          ushort4 o;
          o.x = f2bf(fmap(acc1[i][j][0] + bias[i][0]));
          o.y = f2bf(fmap(acc1[i][j][1] + bias[i][1]));
          o.z = f2bf(fmap(acc1[i][j][2] + bias[i][2]));
          o.w = f2bf(fmap(acc1[i][j][3] + bias[i][3]));
          tile_store4(sQt, nl, mrow + i * 16 + q * 4, o);
        }
    }
    __syncthreads();
    // Qt global write: 8 lanes cover a full 128B row; rows consecutive ->
    // each wave instruction stores 1KB fully contiguous.
    {
      int nr = t >> 3, m0 = (t & 7) * 8;
      uint4 u = tile_frag_u(sQt, nr, m0);
      *(uint4*)(Qt + ((size_t)b * NS + nbase + n0l + nr) * ND + m0) = u;
    }
    // phase 2: KXt_partial += K'[m][n] * x[c'][n] (contract 64 n)
#pragma unroll
    for (int kk = 0; kk < 64; kk += 32) {
      int kb = kk + q * 8;
      bf16x8 af[2], bg[8];
#pragma unroll
      for (int i = 0; i < 2; i++)
        af[i] = tile_frag(sKp, w2m * 32 + i * 16 + l15, kb);
#pragma unroll
      for (int j = 0; j < 8; j++)
        bg[j] = tile_frag(sXN, w2c * 128 + j * 16 + l15, kb);
#pragma unroll
      for (int i = 0; i < 2; i++)
#pragma unroll
        for (int j = 0; j < 8; j++) acc2[i][j] = mfma16(af[i], bg[j], acc2[i][j]);
    }
    __syncthreads();  // protect sXN + overlays before next chunk's stage
  }

  // epilogue: Pp[b][s][m][c'] partial + KsP
  float* pp = Pp + ((size_t)b * SK + s) * ND * NC;
#pragma unroll
  for (int i = 0; i < 2; i++) {
    int mb = w2m * 32 + i * 16 + q * 4;
#pragma unroll
    for (int j = 0; j < 8; j++) {
      int cp = w2c * 128 + j * 16 + l15;
      f32x4 v = acc2[i][j];
#pragma unroll
      for (int r = 0; r < 4; r++) pp[(size_t)(mb + r) * NC + cp] = v[r];
    }
  }
  if (t < 64) KsP[((size_t)b * SK + s) * ND + t] = sKs[t];
}

// ============================================================================
// Kernel C1: reduce split-K partials -> KXt[b][m][c'], Ksum[b][m]
// ============================================================================
__global__ __launch_bounds__(256) void kernelC1(
    const float* __restrict__ Pp, const float* __restrict__ KsP,
    float* __restrict__ KXt, float* __restrict__ Ksum) {
  const int m = blockIdx.x, b = blockIdx.y, t = threadIdx.x;
  float a0 = 0.f, a1 = 0.f;
#pragma unroll 8
  for (int s = 0; s < SK; s++) {
    const float* p = Pp + (((size_t)b * SK + s) * ND + m) * NC;
    a0 += p[t];
    a1 += p[t + 256];
  }
  float* o = KXt + ((size_t)b * ND + m) * NC;
  o[t] = a0;
  o[t + 256] = a1;
  if (t == 0) {
    float ks = 0.f;
    for (int s = 0; s < SK; s++) ks += KsP[((size_t)b * SK + s) * ND + m];
    Ksum[b * ND + m] = ks;
  }
}

// ============================================================================
// Kernel C2: KVT[b][c][m] = sum_c' KXt[m][c'] Wv[c][c'] + Ksum[m]*bv[c]  (bf16)
// One wave per block; block tile [64 c x 64 m], K-loop over 512 c'.
// ============================================================================
__global__ __launch_bounds__(64) void kernelC2(
    const float* __restrict__ KXt, const float* __restrict__ Wv,
    const float* __restrict__ bv, const float* __restrict__ Ksum,
    unsigned short* __restrict__ KVT) {
  __shared__ unsigned short sA[64 * 64];  // Wv rows c
  __shared__ unsigned short sB[64 * 64];  // KXt rows m
  const int t = threadIdx.x;
  const int l15 = t & 15, q = t >> 4;
  const int ct = blockIdx.x, b = blockIdx.y;
  f32x4 acc[4][4];
  const f32x4 zero = {0.f, 0.f, 0.f, 0.f};
  for (int i = 0; i < 4; i++)
    for (int j = 0; j < 4; j++) acc[i][j] = zero;

  for (int c0 = 0; c0 < NC; c0 += 64) {
    __syncthreads();
    int f4 = t & 15;
    for (int it = 0; it < 16; it++) {
      int row = (t >> 4) + it * 4;
      float4 v = *(const float4*)(Wv + ((size_t)(ct * 64 + row)) * NC + c0 + f4 * 4);
      tile_store4(sA, row, f4 * 4,
                  make_ushort4(f2bf(v.x), f2bf(v.y), f2bf(v.z), f2bf(v.w)));
      float4 w = *(const float4*)(KXt + ((size_t)b * ND + row) * NC + c0 + f4 * 4);
      tile_store4(sB, row, f4 * 4,
                  make_ushort4(f2bf(w.x), f2bf(w.y), f2bf(w.z), f2bf(w.w)));
    }
    __syncthreads();
    for (int kk = 0; kk < 64; kk += 32) {
      int kb = kk + q * 8;
      bf16x8 af[4], bg[4];
      for (int i = 0; i < 4; i++) af[i] = tile_frag(sA, i * 16 + l15, kb);
      for (int j = 0; j < 4; j++) bg[j] = tile_frag(sB, j * 16 + l15, kb);
      for (int i = 0; i < 4; i++)
        for (int j = 0; j < 4; j++) acc[i][j] = mfma16(af[i], bg[j], acc[i][j]);
    }
  }
  for (int j = 0; j < 4; j++) {
    int m = j * 16 + l15;
    float ks = Ksum[b * ND + m];
    for (int i = 0; i < 4; i++) {
      for (int r = 0; r < 4; r++) {
        int c = ct * 64 + i * 16 + q * 4 + r;
        float v = acc[i][j][r] + ks * bv[c];
        KVT[((size_t)b * NC + c) * ND + m] = f2bf(v);
      }
    }
  }
}

// ============================================================================
// Kernel D: out[b][c][n] = x + gamma * norm[n] * sum_m KVT[c][m] Qt[n][m]
//   norm[n] = 1 / sum_m Qt[n][m] * (Ksum[m] + EPS)
// Block tile [256 c x 128 n], K=64 (single staging). Grid (N/128, C/256, B).
// ============================================================================
__global__ __launch_bounds__(256) void kernelD(
    const float* __restrict__ x, const unsigned short* __restrict__ Qt,
    const unsigned short* __restrict__ KVT, const float* __restrict__ Ksum,
    const float* __restrict__ gamma, float* __restrict__ out) {
  __shared__ unsigned short sA[256 * 64];  // KVT rows c-local
  __shared__ unsigned short sB[128 * 64];  // Qt rows n-local
  __shared__ float sN[128];
  __shared__ float sKs[64];
  const int t = threadIdx.x;
  const int lane = t & 63, wave = t >> 6;
  const int wm = wave >> 1, wn = wave & 1;  // wave tile 128c x 64n
  const int l15 = lane & 15, q = lane >> 4;
  const int n0 = blockIdx.x * 128;
  const int c0 = blockIdx.y * 256;
  const int b = blockIdx.z;
  if (t < 64) sKs[t] = Ksum[b * ND + t] + FEPS;
  {
    int ch = t & 7;
    for (int it = 0; it < 8; it++) {
      int row = (t >> 3) + it * 32;
      uint4 v = *(const uint4*)(KVT + ((size_t)b * NC + c0 + row) * ND + ch * 8);
      tile_store8(sA, row, ch * 8, v);
    }
    for (int it = 0; it < 4; it++) {
      int row = (t >> 3) + it * 32;
      uint4 v = *(const uint4*)(Qt + ((size_t)b * NS + n0 + row) * ND + ch * 8);
      tile_store8(sB, row, ch * 8, v);
    }
  }
  __syncthreads();
  if (t < 128) {
    float sum = 0.f;
    for (int ch = 0; ch < 8; ch++) {
      const unsigned short* p = sB + t * 64 + ((ch ^ (t & 7)) * 8);
      for (int e = 0; e < 8; e++) sum += bf2f(p[e]) * sKs[ch * 8 + e];
    }
    sN[t] = 1.0f / sum;
  }
  __syncthreads();

  f32x4 acc[8][4];
  const f32x4 zero = {0.f, 0.f, 0.f, 0.f};
  for (int i = 0; i < 8; i++)
    for (int j = 0; j < 4; j++) acc[i][j] = zero;
  for (int kk = 0; kk < 64; kk += 32) {
    int kb = kk + q * 8;
    bf16x8 af[8], bg[4];
    for (int i = 0; i < 8; i++) af[i] = tile_frag(sA, wm * 128 + i * 16 + l15, kb);
    for (int j = 0; j < 4; j++) bg[j] = tile_frag(sB, wn * 64 + j * 16 + l15, kb);
    for (int i = 0; i < 8; i++)
      for (int j = 0; j < 4; j++) acc[i][j] = mfma16(af[i], bg[j], acc[i][j]);
  }
  float g = gamma[0];
  for (int i = 0; i < 8; i++) {
    int cb = c0 + wm * 128 + i * 16 + q * 4;
    for (int j = 0; j < 4; j++) {
      int nl = wn * 64 + j * 16 + l15;
      int n = n0 + nl;
      float nr = sN[nl] * g;
      f32x4 v = acc[i][j];
      for (int r = 0; r < 4; r++) {
        size_t idx = ((size_t)b * NC + cb + r) * NS + n;
        out[idx] = x[idx] + nr * v[r];
      }
    }
  }
}

extern "C" void kernel_launch(void* const* d_in, const int* in_sizes, int n_in,
                              void* d_out, int out_size, void* d_ws, size_t ws_size,
                              hipStream_t stream) {
  (void)in_sizes; (void)n_in; (void)out_size; (void)ws_size;
  const float* x = (const float*)d_in[0];
  const float* Wq = (const float*)d_in[1];
  const float* bq = (const float*)d_in[2];
  const float* Wk = (const float*)d_in[3];
  const float* bk = (const float*)d_in[4];
  const float* Wv = (const float*)d_in[5];
  const float* bv = (const float*)d_in[6];
  const float* gamma = (const float*)d_in[7];
  float* out = (float*)d_out;

  char* ws = (char*)d_ws;
  unsigned short* Qt = (unsigned short*)ws;   ws += (size_t)NB * NS * ND * 2;       // 16.78 MB
  float* Pp = (float*)ws;                     ws += (size_t)NB * SK * ND * NC * 4;  // 33.55 MB
  float* KsP = (float*)ws;                    ws += (size_t)NB * SK * ND * 4;       // 64 KB
  float* KXt = (float*)ws;                    ws += (size_t)NB * ND * NC * 4;       // 1 MB
  float* Ksum = (float*)ws;                   ws += (size_t)NB * ND * 4;            // 2 KB
  unsigned short* KVT = (unsigned short*)ws;  ws += (size_t)NB * NC * ND * 2;       // 0.5 MB
  unsigned short* Wqkb = (unsigned short*)ws; ws += (size_t)2 * ND * NC * 2;        // 128 KB

  kernelP<<<dim3(32), dim3(256), 0, stream>>>(Wq, Wk, Wqkb);
  kernelA<<<dim3(SK, NB), dim3(512), 0, stream>>>(x, Wqkb, bq, bk, Qt, Pp, KsP);
  kernelC1<<<dim3(ND, NB), dim3(256), 0, stream>>>(Pp, KsP, KXt, Ksum);
  kernelC2<<<dim3(NC / 64, NB), dim3(64), 0, stream>>>(KXt, Wv, bv, Ksum, KVT);
  kernelD<<<dim3(NS / 128, NC / 256, NB), dim3(256), 0, stream>>>(x, Qt, KVT, Ksum, gamma, out);
}